// Round 5
// baseline (309.000 us; speedup 1.0000x reference)
//
#include <hip/hip_runtime.h>
#include <stdint.h>

// YOLO loss: S=7, B=2, C=80. preds cell = 90 f32, target cell = 85 f32.
// Output: 4 f32 scalars (coords, obj, noobj, classes), summed over 401408 cells.
//
// v6: pure grid-stride streaming, no LDS staging, no waitcnt choreography.
//   Evidence (r4 post-mortem): three different staged-pipeline structures
//   (v3 reg-burst convoy, v4 global_load_lds convoy, v5 wave-autonomous
//   counted-vmcnt) ALL pin at 115-119us = 2.4 TB/s blended; secondary
//   counters moved, throughput didn't -> the staged/chunked structure itself
//   (few large synchronized bursts, dependent consumption) limits service
//   bandwidth. v6 = RMSNorm-regime: thread->quad coalesced float4 stream of
//   preds (classes loss, targ gathered via L3-resident scalar loads) +
//   thread->cell box phase. Max autonomous waves, max outstanding requests.
//   Pre-committed falsifier: if still ~115us, 2.4 TB/s is the platform blend
//   ceiling for this footprint -> roofline.

#define NPRED 90
#define NTGT  85
#define NCLS  80
#define TPB   256
#define NBLK  2048   // memory-bound: ~cap grid, grid-stride (G11)

__device__ __forceinline__ float sgnf(float x) {
    // matches jnp.sign: sign(0) == 0
    return (x > 0.0f) ? 1.0f : ((x < 0.0f) ? -1.0f : 0.0f);
}

__device__ __forceinline__ float iou_vs_target(
    float acx, float acy, float aw, float ah,
    float bx1, float by1, float bx2, float by2, float area_b)
{
    float ax1 = acx - aw * 0.5f, ay1 = acy - ah * 0.5f;
    float ax2 = acx + aw * 0.5f, ay2 = acy + ah * 0.5f;
    float iw = fmaxf(fminf(ax2, bx2) - fmaxf(ax1, bx1), 0.0f);
    float ih = fmaxf(fminf(ay2, by2) - fmaxf(ay1, by1), 0.0f);
    float inter = iw * ih;
    float area_a = (ax2 - ax1) * (ay2 - ay1);
    return inter / (area_a + area_b - inter);
}

// one preds quad -> classes-loss contribution.
// f = 4q, cl = f/90, j = f%90 (even). j<=76: 4 classes; j==78: 2 classes;
// j==88: x,y box fields (skip), z,w = classes 0,1 of cl+1; else box (skip).
__device__ __forceinline__ void class_quad(
    const float4* __restrict__ pr4, const float* __restrict__ targ,
    long long q, float& clsl)
{
    float4 v = pr4[q];
    unsigned f  = (unsigned)(4ll * q);
    unsigned cl = f / 90u;            // compiler magic-mul
    unsigned j  = f - cl * 90u;
    const float* tb = targ + (size_t)cl * NTGT;
    if (j <= 76u) {
        float obj = tb[NCLS];
        float d0 = fmaf(v.x, obj, -tb[j]);
        float d1 = fmaf(v.y, obj, -tb[j + 1]);
        float d2 = fmaf(v.z, obj, -tb[j + 2]);
        float d3 = fmaf(v.w, obj, -tb[j + 3]);
        clsl = fmaf(d0, d0, clsl);
        clsl = fmaf(d1, d1, clsl);
        clsl = fmaf(d2, d2, clsl);
        clsl = fmaf(d3, d3, clsl);
    } else if (j == 78u) {
        float obj = tb[NCLS];
        float d0 = fmaf(v.x, obj, -tb[78]);
        float d1 = fmaf(v.y, obj, -tb[79]);
        clsl = fmaf(d0, d0, clsl);
        clsl = fmaf(d1, d1, clsl);
    } else if (j == 88u) {
        // z,w wrap to classes 0,1 of cl+1 (cl is even here, cl+1 < n_cells)
        const float* t2 = tb + NTGT;
        float obj2 = t2[NCLS];
        float d0 = fmaf(v.z, obj2, -t2[0]);
        float d1 = fmaf(v.w, obj2, -t2[1]);
        clsl = fmaf(d0, d0, clsl);
        clsl = fmaf(d1, d1, clsl);
    }
    // j in {80,82,84,86}: all box fields, handled by box phase
}

__global__ __launch_bounds__(TPB, 2) void yolo_loss_kernel(
    const float* __restrict__ preds, const float* __restrict__ targ,
    float* __restrict__ part, float* __restrict__ out,
    int n_cells, int mode)
{
    __shared__ float red[4][4];

    float coords = 0.0f, objl = 0.0f, noobjl = 0.0f, clsl = 0.0f;

    const int tid = threadIdx.x;
    const long long tid0    = (long long)blockIdx.x * TPB + tid;
    const long long tstride = (long long)gridDim.x * TPB;

    // ---- classes phase: coalesced float4 stream over preds quads ----
    // (any non-quad tail elements have j>=87 -> box fields -> no class term)
    const long long n_quads = ((long long)n_cells * NPRED) / 4;
    const float4* pr4 = (const float4*)preds;

    long long q = tid0;
    for (; q + tstride < n_quads; q += 2 * tstride) {
        // two independent quads in flight per iteration (MLP)
        class_quad(pr4, targ, q,           clsl);
        class_quad(pr4, targ, q + tstride, clsl);
    }
    for (; q < n_quads; q += tstride)
        class_quad(pr4, targ, q, clsl);

    // ---- box phase: one thread per cell ----
    for (long long c = tid0; c < n_cells; c += tstride) {
        const float* pB = preds + (size_t)c * NPRED + NCLS;  // p[80..89], even -> 8B aligned
        const float* tB = targ  + (size_t)c * NTGT + NCLS;   // t[80..84]
        float2 b0 = *(const float2*)(pB);      // p80 p81
        float2 b1 = *(const float2*)(pB + 2);  // p82 p83
        float2 b2 = *(const float2*)(pB + 4);  // p84 p85
        float2 b3 = *(const float2*)(pB + 6);  // p86 p87
        float2 b4 = *(const float2*)(pB + 8);  // p88 p89
        float obj = tB[0];
        float tcx = tB[1], tcy = tB[2], tw = tB[3], th = tB[4];

        float bx1 = tcx - tw * 0.5f, by1 = tcy - th * 0.5f;
        float bx2 = tcx + tw * 0.5f, by2 = tcy + th * 0.5f;
        float area_b = (bx2 - bx1) * (by2 - by1);

        // box1 = p[86..89], box2 = p[81..84]
        float iou1 = iou_vs_target(b3.x, b3.y, b4.x, b4.y,
                                   bx1, by1, bx2, by2, area_b);
        float iou2 = iou_vs_target(b0.y, b1.x, b1.y, b2.x,
                                   bx1, by1, bx2, by2, area_b);
        bool use2 = iou2 > iou1;  // argmax: tie -> box1

        float pcx = obj * (use2 ? b0.y : b3.x);
        float pw  = obj * (use2 ? b1.y : b4.x);
        float ph  = obj * (use2 ? b2.x : b4.y);

        // center loss uses ONLY cx (ref's [..., :-3] on a 4-vector)
        float dc = pcx - tcx;
        float dw = sgnf(pw) * sqrtf(fabsf(pw) + 1e-6f) - sqrtf(tw);
        float dh = sgnf(ph) * sqrtf(fabsf(ph) + 1e-6f) - sqrtf(th);
        coords = fmaf(dc, dc, coords);
        coords = fmaf(dw, dw, coords);
        coords = fmaf(dh, dh, coords);

        float obj_pred = use2 ? b0.x : b2.y;  // p[80] : p[85]
        float e1 = fmaf(obj, obj_pred, -obj);
        objl = fmaf(e1, e1, objl);
        float e2 = fmaf(1.0f - obj, obj_pred, -obj);
        noobjl = fmaf(e2, e2, noobjl);
    }

    // ---- wave reduce (64 lanes) ----
    #pragma unroll
    for (int off = 32; off > 0; off >>= 1) {
        coords += __shfl_down(coords, off);
        objl   += __shfl_down(objl, off);
        noobjl += __shfl_down(noobjl, off);
        clsl   += __shfl_down(clsl, off);
    }

    int wave = tid >> 6;
    int lane = tid & 63;
    if (lane == 0) {
        red[0][wave] = coords;
        red[1][wave] = objl;
        red[2][wave] = noobjl;
        red[3][wave] = clsl;
    }
    __syncthreads();
    if (tid == 0) {
        float c = red[0][0] + red[0][1] + red[0][2] + red[0][3];
        float o = red[1][0] + red[1][1] + red[1][2] + red[1][3];
        float n = red[2][0] + red[2][1] + red[2][2] + red[2][3];
        float k = red[3][0] + red[3][1] + red[3][2] + red[3][3];
        if (mode == 0) {
            // component-major partials: no contention, plain stores
            int nb = gridDim.x;
            part[0 * nb + blockIdx.x] = c;
            part[1 * nb + blockIdx.x] = o;
            part[2 * nb + blockIdx.x] = n;
            part[3 * nb + blockIdx.x] = k;
        } else {
            atomicAdd(&out[0], 5.0f * c);
            atomicAdd(&out[1], o);
            atomicAdd(&out[2], 0.5f * n);
            atomicAdd(&out[3], k);
        }
    }
}

// one block, 4 waves: wave w reduces component w over nblk partials
__global__ __launch_bounds__(256) void yolo_reduce_kernel(
    const float* __restrict__ part, float* __restrict__ out, int nblk)
{
    int w = threadIdx.x >> 6;
    int lane = threadIdx.x & 63;
    float s = 0.0f;
    for (int i = lane; i < nblk; i += 64) s += part[w * nblk + i];
    #pragma unroll
    for (int off = 32; off > 0; off >>= 1) s += __shfl_down(s, off);
    if (lane == 0) {
        float scale = (w == 0) ? 5.0f : (w == 2) ? 0.5f : 1.0f;
        out[w] = s * scale;  // plain store overwrites poison
    }
}

extern "C" void kernel_launch(void* const* d_in, const int* in_sizes, int n_in,
                              void* d_out, int out_size, void* d_ws, size_t ws_size,
                              hipStream_t stream) {
    const float* preds = (const float*)d_in[0];
    const float* targ  = (const float*)d_in[1];
    float* out = (float*)d_out;

    int n_cells = in_sizes[0] / NPRED;  // 8192*7*7 = 401408

    bool use_ws = ws_size >= (size_t)(4 * NBLK) * sizeof(float);

    if (use_ws) {
        float* part = (float*)d_ws;
        hipLaunchKernelGGL(yolo_loss_kernel, dim3(NBLK), dim3(TPB), 0, stream,
                           preds, targ, part, out, n_cells, 0);
        hipLaunchKernelGGL(yolo_reduce_kernel, dim3(1), dim3(256), 0, stream,
                           part, out, NBLK);
        if (out_size > 4) {
            hipMemsetAsync(out + 4, 0, (size_t)(out_size - 4) * sizeof(float), stream);
        }
    } else {
        // fallback: contended-atomic path (d_out poisoned -> zero first)
        hipMemsetAsync(d_out, 0, (size_t)out_size * sizeof(float), stream);
        hipLaunchKernelGGL(yolo_loss_kernel, dim3(NBLK), dim3(TPB), 0, stream,
                           preds, targ, (float*)nullptr, out, n_cells, 1);
    }
}